// Round 1
// baseline (78.613 us; speedup 1.0000x reference)
//
#include <hip/hip_runtime.h>
#include <math.h>

#define BLK 256
#define CH 3
#define HH 32
#define WW 32
#define INF 3072   // CH*HH*WW
#define PH 34
#define PW 34

__global__ __launch_bounds__(BLK) void fused_point_conv_kernel(
    const float4* __restrict__ x,        // [B, 3072] of float4 (x1,x2,x3,reset)
    const float* __restrict__ tau_m1,    // [3072]
    const float* __restrict__ tau_s1,    // [3072]
    const float* __restrict__ tau_sm1,   // [3072]
    const float* __restrict__ gk,        // [3,3,3,3] OIHW
    const float* __restrict__ gb,        // [3]
    const int*   __restrict__ weight,    // scalar
    float* __restrict__ out)             // [B, 3072]
{
    __shared__ float y[CH][PH][PW];      // zero-padded image tile
    __shared__ float sk[CH * CH * 9];    // conv weights
    __shared__ float sb[CH];

    const int b = blockIdx.x;
    const int t = threadIdx.x;

    // zero the whole padded tile (covers the SAME-padding border)
    float* yflat = &y[0][0][0];
    for (int i = t; i < CH * PH * PW; i += BLK) yflat[i] = 0.f;
    if (t < CH * CH * 9) sk[t] = gk[t];
    if (t < CH) sb[t] = gb[t];

    const float inv2w = exp2f(-(float)weight[0]);

    // phase 1: pointwise y -> LDS (registers first, one barrier total)
    float yy[INF / BLK];
    int   fs[INF / BLK];
    #pragma unroll
    for (int i = 0; i < INF / BLK; ++i) {
        const int f = i * BLK + t;
        fs[i] = f;
        const float4 v = x[(size_t)b * INF + f];
        const float e = (v.x > 0.f) ? v.x : expm1f(v.x);       // elu
        const float l = (v.z >= 0.f) ? v.z : 0.01f * v.z;      // leaky relu
        float r = fmaf(e, tau_m1[f], 0.f);
        r = fmaf(-v.y, tau_s1[f], r);
        r = fmaf(l, tau_sm1[f], r);
        if (v.w > 0.f) r -= inv2w;                             // heaviside spike
        yy[i] = r;
    }
    __syncthreads();   // ensure zero-fill done before interior writes? no —
                       // interior writes below overwrite interior only; border
                       // zeros are written by the same loop above. Barrier here
                       // orders zero-fill (all threads) vs interior writes.
    #pragma unroll
    for (int i = 0; i < INF / BLK; ++i) {
        const int f = fs[i];
        const int c = f >> 10;            // f / 1024
        const int hw = f & 1023;
        const int h = hw >> 5, w = hw & 31;
        y[c][h + 1][w + 1] = yy[i];
    }
    __syncthreads();

    // phase 2: 3x3 SAME conv + bias + clamp, coalesced store
    #pragma unroll
    for (int i = 0; i < INF / BLK; ++i) {
        const int f = i * BLK + t;
        const int c = f >> 10;            // wave-uniform per i
        const int hw = f & 1023;
        const int h = hw >> 5, w = hw & 31;
        float acc = sb[c];
        #pragma unroll
        for (int ci = 0; ci < CH; ++ci)
            #pragma unroll
            for (int kh = 0; kh < 3; ++kh)
                #pragma unroll
                for (int kw = 0; kw < 3; ++kw)
                    acc = fmaf(y[ci][h + kh][w + kw],
                               sk[((c * CH + ci) * 3 + kh) * 3 + kw], acc);
        acc = fminf(fmaxf(acc, -0.7f), 0.7f);
        out[(size_t)b * INF + f] = acc;
    }
}

extern "C" void kernel_launch(void* const* d_in, const int* in_sizes, int n_in,
                              void* d_out, int out_size, void* d_ws, size_t ws_size,
                              hipStream_t stream) {
    const float4* x      = (const float4*)d_in[0];
    const float* tau_m1  = (const float*)d_in[1];
    const float* tau_s1  = (const float*)d_in[2];
    const float* tau_sm1 = (const float*)d_in[3];
    const float* gk      = (const float*)d_in[4];
    const float* gb      = (const float*)d_in[5];
    const int*   weight  = (const int*)d_in[6];
    float* out = (float*)d_out;

    const int B = in_sizes[0] / (INF * 4);   // 4096
    fused_point_conv_kernel<<<B, BLK, 0, stream>>>(
        x, tau_m1, tau_s1, tau_sm1, gk, gb, weight, out);
}

// Round 2
// 49.564 us; speedup vs baseline: 1.5861x; 1.5861x over previous
//
#include <hip/hip_runtime.h>
#include <math.h>

#define BLK 256
#define CH 3
#define INF 3072
#define PH 34
#define PW 36   // row stride 144 B: 16B-aligned rows, w0%4==0 keeps b128 alignment

__device__ __forceinline__ float pointwise(float4 v, float tm, float ts, float tsm,
                                           float inv2w) {
    const float el = (v.x > 0.f) ? v.x : expm1f(v.x);      // elu
    const float lr = (v.z >= 0.f) ? v.z : 0.01f * v.z;     // leaky relu
    float r = el * tm;
    r = fmaf(-v.y, ts, r);
    r = fmaf(lr, tsm, r);
    return (v.w > 0.f) ? r - inv2w : r;                    // heaviside spike
}

__global__ __launch_bounds__(BLK) void fused_point_conv_kernel(
    const float4* __restrict__ x,     // [B, 3072] float4 (x1,x2,x3,reset)
    const float4* __restrict__ tm4,   // tau_m1  as [768] float4
    const float4* __restrict__ ts4,   // tau_s1
    const float4* __restrict__ tsm4,  // tau_sm1
    const float* __restrict__ gk,     // [3,3,3,3] OIHW
    const float* __restrict__ gb,     // [3]
    const int*  __restrict__ weight,  // scalar
    float4* __restrict__ out)         // [B, 768] float4
{
    __shared__ float y[CH][PH][PW];
    __shared__ float sk[CH * CH * 9];
    __shared__ float sb[CH];

    const int b = blockIdx.x;
    const int t = threadIdx.x;

    // Zero ONLY the padding border (interior fully overwritten by phase 1):
    // per channel: row 0 (36) + row 33 (36) + rows 1..32 cols {0,33,34,35} (128) = 200
    for (int i = t; i < CH * 200; i += BLK) {
        const int c = i / 200;
        const int r = i - c * 200;
        int row, col;
        if (r < 36)      { row = 0;  col = r; }
        else if (r < 72) { row = 33; col = r - 36; }
        else { const int rr = r - 72; row = 1 + (rr >> 2);
               const int sel = rr & 3; col = (sel == 0) ? 0 : 32 + sel; }
        y[c][row][col] = 0.f;
    }
    if (t < CH * CH * 9) sk[t] = gk[t];
    if (t < CH) sb[t] = gb[t];

    const float inv2w = exp2f(-(float)weight[0]);
    const int h  = t >> 3;          // 0..31
    const int w0 = (t & 7) << 2;    // 0,4,...,28
    const size_t xbase = (size_t)b * INF;

    __syncthreads();   // border zeros visible before interior writes complete mix

    // phase 1: pointwise, quad per thread per channel j
    #pragma unroll
    for (int j = 0; j < 3; ++j) {
        const int f0 = (j << 10) + (t << 2);      // first of 4 consecutive features
        const float4 v0 = x[xbase + f0 + 0];
        const float4 v1 = x[xbase + f0 + 1];
        const float4 v2 = x[xbase + f0 + 2];
        const float4 v3 = x[xbase + f0 + 3];
        const int q = (j << 8) + t;
        const float4 tm = tm4[q], ts = ts4[q], tsm = tsm4[q];
        float* yrow = &y[j][h + 1][w0 + 1];
        yrow[0] = pointwise(v0, tm.x, ts.x, tsm.x, inv2w);
        yrow[1] = pointwise(v1, tm.y, ts.y, tsm.y, inv2w);
        yrow[2] = pointwise(v2, tm.z, ts.z, tsm.z, inv2w);
        yrow[3] = pointwise(v3, tm.w, ts.w, tsm.w, inv2w);
    }
    __syncthreads();

    // phase 2: 3x3 SAME conv, 4 outputs/thread/channel via 6-float strips
    #pragma unroll
    for (int j = 0; j < 3; ++j) {
        const float bias = sb[j];
        float a0 = bias, a1 = bias, a2 = bias, a3 = bias;
        #pragma unroll
        for (int ci = 0; ci < CH; ++ci) {
            #pragma unroll
            for (int kh = 0; kh < 3; ++kh) {
                const float4 s4 = *(const float4*)&y[ci][h + kh][w0];      // ds_read_b128
                const float2 s2 = *(const float2*)&y[ci][h + kh][w0 + 4];  // ds_read_b64
                const int kb = ((j * CH + ci) * 3 + kh) * 3;
                const float k0 = sk[kb + 0], k1 = sk[kb + 1], k2 = sk[kb + 2];
                a0 = fmaf(s4.x, k0, a0); a0 = fmaf(s4.y, k1, a0); a0 = fmaf(s4.z, k2, a0);
                a1 = fmaf(s4.y, k0, a1); a1 = fmaf(s4.z, k1, a1); a1 = fmaf(s4.w, k2, a1);
                a2 = fmaf(s4.z, k0, a2); a2 = fmaf(s4.w, k1, a2); a2 = fmaf(s2.x, k2, a2);
                a3 = fmaf(s4.w, k0, a3); a3 = fmaf(s2.x, k1, a3); a3 = fmaf(s2.y, k2, a3);
            }
        }
        a0 = fminf(fmaxf(a0, -0.7f), 0.7f);
        a1 = fminf(fmaxf(a1, -0.7f), 0.7f);
        a2 = fminf(fmaxf(a2, -0.7f), 0.7f);
        a3 = fminf(fmaxf(a3, -0.7f), 0.7f);
        out[(size_t)b * (INF / 4) + (j << 8) + t] = make_float4(a0, a1, a2, a3);
    }
}

extern "C" void kernel_launch(void* const* d_in, const int* in_sizes, int n_in,
                              void* d_out, int out_size, void* d_ws, size_t ws_size,
                              hipStream_t stream) {
    const float4* x    = (const float4*)d_in[0];
    const float4* tm4  = (const float4*)d_in[1];
    const float4* ts4  = (const float4*)d_in[2];
    const float4* tsm4 = (const float4*)d_in[3];
    const float*  gk   = (const float*)d_in[4];
    const float*  gb   = (const float*)d_in[5];
    const int*    wgt  = (const int*)d_in[6];
    float4* out = (float4*)d_out;

    const int B = in_sizes[0] / (INF * 4);   // 4096
    fused_point_conv_kernel<<<B, BLK, 0, stream>>>(
        x, tm4, ts4, tsm4, gk, gb, wgt, out);
}